// Round 9
// baseline (73.930 us; speedup 1.0000x reference)
//
#include <hip/hip_runtime.h>

#define N_NODES 40000
#define C_DIM   128
#define K_NBR   16

static constexpr float BETA_F  = 0.11778303565638346f;  // log(1.125)
static constexpr float C1_F    = 0.7939952679092549f;   // (1-ALPHA)*(1-BETA)
static constexpr float C2_F    = 0.08822169643436166f;  // ALPHA*(1-BETA)
static constexpr float SCALE_X  = BETA_F / 17.0f;       // applied to x
static constexpr float SCALE_X0 = BETA_F;               // applied to x0
static constexpr float CD1_F = C1_F / BETA_F;           // diag coeff vs scaled x
static constexpr float CD2_F = C2_F / BETA_F;           // diag coeff vs scaled x0

typedef __attribute__((ext_vector_type(8))) short bf16x8;
typedef __attribute__((ext_vector_type(4))) float f32x4;

__device__ __forceinline__ unsigned pack_bf16x2(float a, float b) {
    unsigned ua = __float_as_uint(a), ub = __float_as_uint(b);
    ua += 0x7fffu + ((ua >> 16) & 1u);     // RNE
    ub += 0x7fffu + ((ub >> 16) & 1u);
    return (ua >> 16) | (ub & 0xffff0000u);
}
__device__ __forceinline__ float bflo(unsigned u) { return __uint_as_float(u << 16); }
__device__ __forceinline__ float bfhi(unsigned u) { return __uint_as_float(u & 0xffff0000u); }

// B-fragment from 8 consecutive f32 weights, + diag fold at element d (0..7).
__device__ __forceinline__ bf16x8 pack_w8_diag(const float* wp, int d, float dg) {
    float4 wa = *(const float4*)wp;
    float4 wb = *(const float4*)(wp + 4);
    wa.x += (d == 0) ? dg : 0.0f;
    wa.y += (d == 1) ? dg : 0.0f;
    wa.z += (d == 2) ? dg : 0.0f;
    wa.w += (d == 3) ? dg : 0.0f;
    wb.x += (d == 4) ? dg : 0.0f;
    wb.y += (d == 5) ? dg : 0.0f;
    wb.z += (d == 6) ? dg : 0.0f;
    wb.w += (d == 7) ? dg : 0.0f;
    uint4 uu = make_uint4(pack_bf16x2(wa.x, wa.y), pack_bf16x2(wa.z, wa.w),
                          pack_bf16x2(wb.x, wb.y), pack_bf16x2(wb.z, wb.w));
    return *(bf16x8*)&uu;
}

// ---------------------------------------------------------------------------
// Kernel 1 (zprep), grid 2500:
//  role A (b<1250):  z1T[n][o] = bf16( (B/17)*sum_c x[c][n]W1[o][c] + (C1/17)x[o][n] )
//  role B (b>=1250): z2T[n][o] = bf16( B*sum_c x0[n][c]W2[o][c] + C2*x0[n][o] + bias[o] )
// Diag folded into W fragments; results go f32->LDS->coalesced uint4 stores
// (full 256-B rows; R8's even-lane scattered u32 z1 stores were partial-line).
// ---------------------------------------------------------------------------
__global__ __launch_bounds__(256) void zprep_kernel(
        const float* __restrict__ x,      // [128][40000]
        const float* __restrict__ x0,     // [40000][128]
        const float* __restrict__ W1,     // [128][128]
        const float* __restrict__ W2,     // [128][128]
        const float* __restrict__ bias,   // [128]
        unsigned* __restrict__ z1T,       // [N][64] u32 = bf16x2
        unsigned* __restrict__ z2T) {     // [N][64] u32 = bf16x2
    __shared__ unsigned xs[32 * 68];      // staged scaled input, bf16x2
    __shared__ float    zb[32 * 132];     // f32 result tile

    const int b    = blockIdx.x;
    const bool roleA = (b < 1250);
    const int nb   = (roleA ? b : (b - 1250)) * 32;
    const int tid  = threadIdx.x;

    if (roleA) {
        // transpose+cast+scale 32n x 128c of x (R7/R8-proven pattern)
        const int c2 = tid >> 2;          // 0..63
        const int h  = tid & 3;           // n-offset h*8
        const float* r0 = &x[(size_t)(2 * c2)     * N_NODES + nb + h * 8];
        const float* r1 = &x[(size_t)(2 * c2 + 1) * N_NODES + nb + h * 8];
        const float4 a0 = *(const float4*)(r0);
        const float4 a1 = *(const float4*)(r0 + 4);
        const float4 b0 = *(const float4*)(r1);
        const float4 b1 = *(const float4*)(r1 + 4);
        unsigned* lr = &xs[(h * 8) * 68 + c2];
        lr[0 * 68] = pack_bf16x2(a0.x * SCALE_X, b0.x * SCALE_X);
        lr[1 * 68] = pack_bf16x2(a0.y * SCALE_X, b0.y * SCALE_X);
        lr[2 * 68] = pack_bf16x2(a0.z * SCALE_X, b0.z * SCALE_X);
        lr[3 * 68] = pack_bf16x2(a0.w * SCALE_X, b0.w * SCALE_X);
        lr[4 * 68] = pack_bf16x2(a1.x * SCALE_X, b1.x * SCALE_X);
        lr[5 * 68] = pack_bf16x2(a1.y * SCALE_X, b1.y * SCALE_X);
        lr[6 * 68] = pack_bf16x2(a1.z * SCALE_X, b1.z * SCALE_X);
        lr[7 * 68] = pack_bf16x2(a1.w * SCALE_X, b1.w * SCALE_X);
    } else {
        // stage scaled x0 rows (already [n][c]; coalesced 512 B per row)
        const int n = tid >> 3, g = tid & 7;
        const float* r = &x0[(size_t)(nb + n) * C_DIM + g * 16];
        const float4 v0 = *(const float4*)(r);
        const float4 v1 = *(const float4*)(r + 4);
        const float4 v2 = *(const float4*)(r + 8);
        const float4 v3 = *(const float4*)(r + 12);
        uint4 ua, ub;
        ua.x = pack_bf16x2(v0.x * SCALE_X0, v0.y * SCALE_X0);
        ua.y = pack_bf16x2(v0.z * SCALE_X0, v0.w * SCALE_X0);
        ua.z = pack_bf16x2(v1.x * SCALE_X0, v1.y * SCALE_X0);
        ua.w = pack_bf16x2(v1.z * SCALE_X0, v1.w * SCALE_X0);
        ub.x = pack_bf16x2(v2.x * SCALE_X0, v2.y * SCALE_X0);
        ub.y = pack_bf16x2(v2.z * SCALE_X0, v2.w * SCALE_X0);
        ub.z = pack_bf16x2(v3.x * SCALE_X0, v3.y * SCALE_X0);
        ub.w = pack_bf16x2(v3.z * SCALE_X0, v3.w * SCALE_X0);
        *(uint4*)&xs[n * 68 + g * 8]     = ua;
        *(uint4*)&xs[n * 68 + g * 8 + 4] = ub;
    }
    __syncthreads();

    // ---- MFMA: [32n x 128c] x W^T -> [32n x 128o] ----
    const int lane = tid & 63;
    const int wid  = tid >> 6;
    const int nh = wid & 1, oh = wid >> 1;
    const int arow = nh * 16 + (lane & 15);
    const int acol = (lane >> 4) * 4;

    bf16x8 af[4];
#pragma unroll
    for (int kb = 0; kb < 4; ++kb)
        af[kb] = *(const bf16x8*)&xs[arow * 68 + kb * 16 + acol];

    const int ob = oh * 64 + (lane & 15);
    const int cbq = (lane >> 4) * 8;
    const int rbase = nh * 16 + (lane >> 4) * 4;
    const float* W  = roleA ? W1 : W2;
    const float dg  = roleA ? CD1_F : CD2_F;

#pragma unroll
    for (int t = 0; t < 4; ++t) {
        const int o = ob + t * 16;
        f32x4 a = {0.f, 0.f, 0.f, 0.f};
#pragma unroll
        for (int kb = 0; kb < 4; ++kb) {
            const int cbase = kb * 32 + cbq;
            const bf16x8 bw = pack_w8_diag(&W[(size_t)o * C_DIM + cbase], o - cbase, dg);
            a = __builtin_amdgcn_mfma_f32_16x16x32_bf16(af[kb], bw, a, 0, 0, 0);
        }
#pragma unroll
        for (int r = 0; r < 4; ++r)
            zb[(rbase + r) * 132 + o] = a[r];
    }
    __syncthreads();

    // ---- pack + coalesced store (wave = 8 complete 256-B rows) ----
    const int n = tid >> 3, g = tid & 7;
    const float* zr = &zb[n * 132 + g * 16];
    float v[16];
#pragma unroll
    for (int i = 0; i < 16; i += 4) {
        const float4 q = *(const float4*)(zr + i);
        v[i] = q.x; v[i + 1] = q.y; v[i + 2] = q.z; v[i + 3] = q.w;
    }
    if (!roleA) {
        const float4 b0 = *(const float4*)&bias[g * 16];
        const float4 b1 = *(const float4*)&bias[g * 16 + 4];
        const float4 b2 = *(const float4*)&bias[g * 16 + 8];
        const float4 b3 = *(const float4*)&bias[g * 16 + 12];
        v[0] += b0.x; v[1] += b0.y; v[2]  += b0.z; v[3]  += b0.w;
        v[4] += b1.x; v[5] += b1.y; v[6]  += b1.z; v[7]  += b1.w;
        v[8] += b2.x; v[9] += b2.y; v[10] += b2.z; v[11] += b2.w;
        v[12] += b3.x; v[13] += b3.y; v[14] += b3.z; v[15] += b3.w;
    }
    uint4 ua, ub;
    ua.x = pack_bf16x2(v[0],  v[1]);  ua.y = pack_bf16x2(v[2],  v[3]);
    ua.z = pack_bf16x2(v[4],  v[5]);  ua.w = pack_bf16x2(v[6],  v[7]);
    ub.x = pack_bf16x2(v[8],  v[9]);  ub.y = pack_bf16x2(v[10], v[11]);
    ub.z = pack_bf16x2(v[12], v[13]); ub.w = pack_bf16x2(v[14], v[15]);
    unsigned* dst = (roleA ? z1T : z2T) + (size_t)(nb + n) * 64 + g * 8;
    *(uint4*)&dst[0] = ua;
    *(uint4*)&dst[4] = ub;
}

// ---------------------------------------------------------------------------
// Kernel 2 (gatherf), grid 1250: out[o][n] = relu( sum_{j in N+(n)} z1T[j]
//                                                  + z2T[n] )
// Pure gather: no MFMA, no W, low VGPR -> all 18 row-loads batch in flight.
// ---------------------------------------------------------------------------
__global__ __launch_bounds__(256) void gatherf_kernel(
        const unsigned* __restrict__ z1T,   // [N][64] u32 = bf16x2
        const unsigned* __restrict__ z2T,   // [N][64] u32 = bf16x2
        const int*      __restrict__ e0,    // [N][16]
        float*          __restrict__ out) { // [128][N]
    __shared__ int   eis[512];
    __shared__ float zbuf[32 * 132];

    const int nb  = blockIdx.x * 32;
    const int tid = threadIdx.x;

    eis[tid]       = e0[(size_t)nb * K_NBR + tid];
    eis[256 + tid] = e0[(size_t)nb * K_NBR + 256 + tid];
    __syncthreads();

    const int hw = tid >> 5, l5 = tid & 31;
#pragma unroll 1
    for (int p = 0; p < 4; ++p) {
        const int local = hw * 4 + p;
        const int n = nb + local;
        const uint2 zv = *(const uint2*)&z2T[(size_t)n * 64 + 2 * l5];
        const uint2 sv = *(const uint2*)&z1T[(size_t)n * 64 + 2 * l5];
        float s0 = bflo(sv.x) + bflo(zv.x);
        float s1 = bfhi(sv.x) + bfhi(zv.x);
        float s2 = bflo(sv.y) + bflo(zv.y);
        float s3 = bfhi(sv.y) + bfhi(zv.y);
        const int* ep = &eis[local * K_NBR];
#pragma unroll
        for (int k = 0; k < K_NBR; ++k) {
            const int j = ep[k];
            const uint2 vv = *(const uint2*)&z1T[(size_t)j * 64 + 2 * l5];
            s0 += bflo(vv.x); s1 += bfhi(vv.x);
            s2 += bflo(vv.y); s3 += bfhi(vv.y);
        }
        f32x4 res;
        res[0] = fmaxf(s0, 0.f); res[1] = fmaxf(s1, 0.f);
        res[2] = fmaxf(s2, 0.f); res[3] = fmaxf(s3, 0.f);
        *(f32x4*)&zbuf[local * 132 + 4 * l5] = res;
    }
    __syncthreads();

    // ---- transpose-store: full 128-B out lines per (o, half) pair ----
    const int o  = tid >> 1;
    const int hh = tid & 1;
    float* op = &out[(size_t)o * N_NODES + nb + hh * 16];
#pragma unroll
    for (int m = 0; m < 4; ++m) {
        const int r = hh * 16 + 4 * m;
        float4 v;
        v.x = zbuf[(r + 0) * 132 + o];
        v.y = zbuf[(r + 1) * 132 + o];
        v.z = zbuf[(r + 2) * 132 + o];
        v.w = zbuf[(r + 3) * 132 + o];
        *(float4*)(op + 4 * m) = v;
    }
}

// ---------------------------------------------------------------------------
extern "C" void kernel_launch(void* const* d_in, const int* in_sizes, int n_in,
                              void* d_out, int out_size, void* d_ws, size_t ws_size,
                              hipStream_t stream) {
    const float* x    = (const float*)d_in[0];   // [1,128,40000,1]
    const float* x0   = (const float*)d_in[1];   // [1,40000,128]
    const int*   ei   = (const int*)  d_in[2];   // [2,1,40000,16]; row 0
    const float* W1   = (const float*)d_in[3];   // [128,128]
    const float* W2   = (const float*)d_in[4];   // [128,128]
    const float* bias = (const float*)d_in[5];   // [128]
    float* out = (float*)d_out;                  // [1,128,40000,1]

    // ws: [0, 10.24MB) z1T ; [10.24MB, 20.48MB) z2T
    unsigned* z1T = (unsigned*)d_ws;
    unsigned* z2T = (unsigned*)((char*)d_ws + (size_t)N_NODES * 64 * 4);

    hipLaunchKernelGGL(zprep_kernel, dim3(2500), dim3(256), 0, stream,
                       x, x0, W1, W2, bias, z1T, z2T);
    hipLaunchKernelGGL(gatherf_kernel, dim3(1250), dim3(256), 0, stream,
                       z1T, z2T, ei, out);
}

// Round 10
// 51.591 us; speedup vs baseline: 1.4330x; 1.4330x over previous
//
#include <hip/hip_runtime.h>

#define N_NODES 40000
#define C_DIM   128
#define K_NBR   16

static constexpr float BETA_F  = 0.11778303565638346f;  // log(1.125)
static constexpr float C1_F    = 0.7939952679092549f;   // (1-ALPHA)*(1-BETA)
static constexpr float C2_F    = 0.08822169643436166f;  // ALPHA*(1-BETA)
static constexpr float SCALE_X  = BETA_F / 17.0f;       // applied to x
static constexpr float SCALE_X0 = BETA_F;               // applied to x0
static constexpr float CD1_F = C1_F / BETA_F;           // diag coeff vs scaled x
static constexpr float CD2_F = C2_F / BETA_F;           // diag coeff vs scaled x0

typedef __attribute__((ext_vector_type(8))) short bf16x8;
typedef __attribute__((ext_vector_type(4))) float f32x4;

__device__ __forceinline__ unsigned pack_bf16x2(float a, float b) {
    unsigned ua = __float_as_uint(a), ub = __float_as_uint(b);
    ua += 0x7fffu + ((ua >> 16) & 1u);     // RNE
    ub += 0x7fffu + ((ub >> 16) & 1u);
    return (ua >> 16) | (ub & 0xffff0000u);
}
__device__ __forceinline__ float bflo(unsigned u) { return __uint_as_float(u << 16); }
__device__ __forceinline__ float bfhi(unsigned u) { return __uint_as_float(u & 0xffff0000u); }

// ---------------------------------------------------------------------------
// Kernel 0 (wprep), grid 128: build frag-major bf16 fragments of W1+diag(CD1)
// and W2+diag(CD2), ONCE (R9 re-packed W inside every one of 2500 zprep
// blocks = 50 us of redundant VALU).  K=128 -> 4 k-blocks, 32 frags per W.
// Fragment map = A-frag slot map: f = otile*4 + kblk;
// elem(lane,j): o = otile*16 + (lane&15), c = kblk*32 + (lane>>4)*8 + j.
// ---------------------------------------------------------------------------
__global__ __launch_bounds__(256) void wprep_kernel(
        const float* __restrict__ W1,
        const float* __restrict__ W2,
        unsigned short* __restrict__ WB1,
        unsigned short* __restrict__ WB2) {
    const int b = blockIdx.x;
    const bool roleA = (b < 64);
    const int i = (roleA ? b : b - 64) * 256 + threadIdx.x;   // 0..16383
    const int frag = i >> 9, within = i & 511;
    const int lane = within >> 3, j = within & 7;
    const int otile = frag >> 2, kblk = frag & 3;
    const int o = otile * 16 + (lane & 15);
    const int c = kblk * 32 + ((lane >> 4) << 3) + j;
    const float* W = roleA ? W1 : W2;
    const float dg = roleA ? CD1_F : CD2_F;
    float v = W[o * C_DIM + c] + (c == o ? dg : 0.0f);
    unsigned u = __float_as_uint(v);
    u += 0x7fffu + ((u >> 16) & 1u);
    (roleA ? WB1 : WB2)[i] = (unsigned short)(u >> 16);
}

// ---------------------------------------------------------------------------
// Kernel 1 (zprep), grid 2500:
//  role A (b<1250):  z1T[n][o] = bf16( (B/17)*sum_c x[c][n]W1[o][c] + (C1/17)x[o][n] )
//  role B (b>=1250): z2T[n][o] = bf16( B*sum_c x0[n][c]W2[o][c] + C2*x0[n][o] + bias[o] )
// W fragments pre-packed (wprep): coalesced 1-KB bf16x8 loads, L2-hit.
// ---------------------------------------------------------------------------
__global__ __launch_bounds__(256) void zprep_kernel(
        const float* __restrict__ x,      // [128][40000]
        const float* __restrict__ x0,     // [40000][128]
        const bf16x8* __restrict__ WB1,   // 32 frags x 64 lanes
        const bf16x8* __restrict__ WB2,
        const float* __restrict__ bias,   // [128]
        unsigned* __restrict__ z1T,       // [N][64] u32 = bf16x2
        unsigned* __restrict__ z2T) {     // [N][64] u32 = bf16x2
    __shared__ unsigned xs[32 * 68];      // staged scaled input, bf16x2
    __shared__ float    zb[32 * 132];     // f32 result tile

    const int b    = blockIdx.x;
    const bool roleA = (b < 1250);
    const int nb   = (roleA ? b : (b - 1250)) * 32;
    const int tid  = threadIdx.x;

    if (roleA) {
        // transpose+cast+scale 32n x 128c of x (R7-proven pattern)
        const int c2 = tid >> 2;          // 0..63
        const int h  = tid & 3;           // n-offset h*8
        const float* r0 = &x[(size_t)(2 * c2)     * N_NODES + nb + h * 8];
        const float* r1 = &x[(size_t)(2 * c2 + 1) * N_NODES + nb + h * 8];
        const float4 a0 = *(const float4*)(r0);
        const float4 a1 = *(const float4*)(r0 + 4);
        const float4 b0 = *(const float4*)(r1);
        const float4 b1 = *(const float4*)(r1 + 4);
        unsigned* lr = &xs[(h * 8) * 68 + c2];
        lr[0 * 68] = pack_bf16x2(a0.x * SCALE_X, b0.x * SCALE_X);
        lr[1 * 68] = pack_bf16x2(a0.y * SCALE_X, b0.y * SCALE_X);
        lr[2 * 68] = pack_bf16x2(a0.z * SCALE_X, b0.z * SCALE_X);
        lr[3 * 68] = pack_bf16x2(a0.w * SCALE_X, b0.w * SCALE_X);
        lr[4 * 68] = pack_bf16x2(a1.x * SCALE_X, b1.x * SCALE_X);
        lr[5 * 68] = pack_bf16x2(a1.y * SCALE_X, b1.y * SCALE_X);
        lr[6 * 68] = pack_bf16x2(a1.z * SCALE_X, b1.z * SCALE_X);
        lr[7 * 68] = pack_bf16x2(a1.w * SCALE_X, b1.w * SCALE_X);
    } else {
        // stage scaled x0 rows (already [n][c]; coalesced 512 B per row)
        const int n = tid >> 3, g = tid & 7;
        const float* r = &x0[(size_t)(nb + n) * C_DIM + g * 16];
        const float4 v0 = *(const float4*)(r);
        const float4 v1 = *(const float4*)(r + 4);
        const float4 v2 = *(const float4*)(r + 8);
        const float4 v3 = *(const float4*)(r + 12);
        uint4 ua, ub;
        ua.x = pack_bf16x2(v0.x * SCALE_X0, v0.y * SCALE_X0);
        ua.y = pack_bf16x2(v0.z * SCALE_X0, v0.w * SCALE_X0);
        ua.z = pack_bf16x2(v1.x * SCALE_X0, v1.y * SCALE_X0);
        ua.w = pack_bf16x2(v1.z * SCALE_X0, v1.w * SCALE_X0);
        ub.x = pack_bf16x2(v2.x * SCALE_X0, v2.y * SCALE_X0);
        ub.y = pack_bf16x2(v2.z * SCALE_X0, v2.w * SCALE_X0);
        ub.z = pack_bf16x2(v3.x * SCALE_X0, v3.y * SCALE_X0);
        ub.w = pack_bf16x2(v3.z * SCALE_X0, v3.w * SCALE_X0);
        *(uint4*)&xs[n * 68 + g * 8]     = ua;
        *(uint4*)&xs[n * 68 + g * 8 + 4] = ub;
    }
    __syncthreads();

    // ---- MFMA: [32n x 128c] x W'^T -> [32n x 128o] ----
    const int lane = tid & 63;
    const int wid  = tid >> 6;
    const int nh = wid & 1, oh = wid >> 1;
    const int arow = nh * 16 + (lane & 15);
    const int acol = (lane >> 4) * 4;

    bf16x8 af[4];
#pragma unroll
    for (int kb = 0; kb < 4; ++kb)
        af[kb] = *(const bf16x8*)&xs[arow * 68 + kb * 16 + acol];

    const int rbase = nh * 16 + (lane >> 4) * 4;
    const bf16x8* WB = roleA ? WB1 : WB2;

#pragma unroll
    for (int t = 0; t < 4; ++t) {
        f32x4 a = {0.f, 0.f, 0.f, 0.f};
#pragma unroll
        for (int kb = 0; kb < 4; ++kb) {
            const bf16x8 bw = WB[((oh * 4 + t) * 4 + kb) * 64 + lane];
            a = __builtin_amdgcn_mfma_f32_16x16x32_bf16(af[kb], bw, a, 0, 0, 0);
        }
        const int o = oh * 64 + t * 16 + (lane & 15);
#pragma unroll
        for (int r = 0; r < 4; ++r)
            zb[(rbase + r) * 132 + o] = a[r];
    }
    __syncthreads();

    // ---- pack + coalesced store (wave = 8 complete 256-B rows) ----
    const int n = tid >> 3, g = tid & 7;
    const float* zr = &zb[n * 132 + g * 16];
    float v[16];
#pragma unroll
    for (int i = 0; i < 16; i += 4) {
        const float4 q = *(const float4*)(zr + i);
        v[i] = q.x; v[i + 1] = q.y; v[i + 2] = q.z; v[i + 3] = q.w;
    }
    if (!roleA) {
        const float4 b0 = *(const float4*)&bias[g * 16];
        const float4 b1 = *(const float4*)&bias[g * 16 + 4];
        const float4 b2 = *(const float4*)&bias[g * 16 + 8];
        const float4 b3 = *(const float4*)&bias[g * 16 + 12];
        v[0] += b0.x; v[1] += b0.y; v[2]  += b0.z; v[3]  += b0.w;
        v[4] += b1.x; v[5] += b1.y; v[6]  += b1.z; v[7]  += b1.w;
        v[8] += b2.x; v[9] += b2.y; v[10] += b2.z; v[11] += b2.w;
        v[12] += b3.x; v[13] += b3.y; v[14] += b3.z; v[15] += b3.w;
    }
    uint4 ua, ub;
    ua.x = pack_bf16x2(v[0],  v[1]);  ua.y = pack_bf16x2(v[2],  v[3]);
    ua.z = pack_bf16x2(v[4],  v[5]);  ua.w = pack_bf16x2(v[6],  v[7]);
    ub.x = pack_bf16x2(v[8],  v[9]);  ub.y = pack_bf16x2(v[10], v[11]);
    ub.z = pack_bf16x2(v[12], v[13]); ub.w = pack_bf16x2(v[14], v[15]);
    unsigned* dst = (roleA ? z1T : z2T) + (size_t)(nb + n) * 64 + g * 8;
    *(uint4*)&dst[0] = ua;
    *(uint4*)&dst[4] = ub;
}

// ---------------------------------------------------------------------------
// Kernel 2 (gatherf), grid 1250: out[o][n] = relu( sum_{j in N+(n)} z1T[j]
//                                                  + z2T[n] )
// Pure gather: no MFMA, no W, low VGPR -> all 18 row-loads batch in flight.
// ---------------------------------------------------------------------------
__global__ __launch_bounds__(256) void gatherf_kernel(
        const unsigned* __restrict__ z1T,   // [N][64] u32 = bf16x2
        const unsigned* __restrict__ z2T,   // [N][64] u32 = bf16x2
        const int*      __restrict__ e0,    // [N][16]
        float*          __restrict__ out) { // [128][N]
    __shared__ int   eis[512];
    __shared__ float zbuf[32 * 132];

    const int nb  = blockIdx.x * 32;
    const int tid = threadIdx.x;

    eis[tid]       = e0[(size_t)nb * K_NBR + tid];
    eis[256 + tid] = e0[(size_t)nb * K_NBR + 256 + tid];
    __syncthreads();

    const int hw = tid >> 5, l5 = tid & 31;
#pragma unroll 1
    for (int p = 0; p < 4; ++p) {
        const int local = hw * 4 + p;
        const int n = nb + local;
        const uint2 zv = *(const uint2*)&z2T[(size_t)n * 64 + 2 * l5];
        const uint2 sv = *(const uint2*)&z1T[(size_t)n * 64 + 2 * l5];
        float s0 = bflo(sv.x) + bflo(zv.x);
        float s1 = bfhi(sv.x) + bfhi(zv.x);
        float s2 = bflo(sv.y) + bflo(zv.y);
        float s3 = bfhi(sv.y) + bfhi(zv.y);
        const int* ep = &eis[local * K_NBR];
#pragma unroll
        for (int k = 0; k < K_NBR; ++k) {
            const int j = ep[k];
            const uint2 vv = *(const uint2*)&z1T[(size_t)j * 64 + 2 * l5];
            s0 += bflo(vv.x); s1 += bfhi(vv.x);
            s2 += bflo(vv.y); s3 += bfhi(vv.y);
        }
        f32x4 res;
        res[0] = fmaxf(s0, 0.f); res[1] = fmaxf(s1, 0.f);
        res[2] = fmaxf(s2, 0.f); res[3] = fmaxf(s3, 0.f);
        *(f32x4*)&zbuf[local * 132 + 4 * l5] = res;
    }
    __syncthreads();

    // ---- transpose-store: full 128-B out lines per (o, half) pair ----
    const int o  = tid >> 1;
    const int hh = tid & 1;
    float* op = &out[(size_t)o * N_NODES + nb + hh * 16];
#pragma unroll
    for (int m = 0; m < 4; ++m) {
        const int r = hh * 16 + 4 * m;
        float4 v;
        v.x = zbuf[(r + 0) * 132 + o];
        v.y = zbuf[(r + 1) * 132 + o];
        v.z = zbuf[(r + 2) * 132 + o];
        v.w = zbuf[(r + 3) * 132 + o];
        *(float4*)(op + 4 * m) = v;
    }
}

// ---------------------------------------------------------------------------
extern "C" void kernel_launch(void* const* d_in, const int* in_sizes, int n_in,
                              void* d_out, int out_size, void* d_ws, size_t ws_size,
                              hipStream_t stream) {
    const float* x    = (const float*)d_in[0];   // [1,128,40000,1]
    const float* x0   = (const float*)d_in[1];   // [1,40000,128]
    const int*   ei   = (const int*)  d_in[2];   // [2,1,40000,16]; row 0
    const float* W1   = (const float*)d_in[3];   // [128,128]
    const float* W2   = (const float*)d_in[4];   // [128,128]
    const float* bias = (const float*)d_in[5];   // [128]
    float* out = (float*)d_out;                  // [1,128,40000,1]

    // ws: [0,32K) WB1 ; [32K,64K) WB2 ; [64K, +10.24M) z1T ; then z2T
    unsigned short* WB1 = (unsigned short*)d_ws;
    unsigned short* WB2 = (unsigned short*)((char*)d_ws + 32768);
    unsigned* z1T = (unsigned*)((char*)d_ws + 65536);
    unsigned* z2T = (unsigned*)((char*)d_ws + 65536 + (size_t)N_NODES * 64 * 4);

    hipLaunchKernelGGL(wprep_kernel, dim3(128), dim3(256), 0, stream,
                       W1, W2, WB1, WB2);
    hipLaunchKernelGGL(zprep_kernel, dim3(2500), dim3(256), 0, stream,
                       x, x0, (const bf16x8*)WB1, (const bf16x8*)WB2, bias,
                       z1T, z2T);
    hipLaunchKernelGGL(gatherf_kernel, dim3(1250), dim3(256), 0, stream,
                       z1T, z2T, ei, out);
}

// Round 11
// 40.599 us; speedup vs baseline: 1.8210x; 1.2708x over previous
//
#include <hip/hip_runtime.h>

#define N_NODES 40000
#define C_DIM   128
#define K_NBR   16

static constexpr float BETA_F  = 0.11778303565638346f;  // log(1.125)
static constexpr float C1_F    = 0.7939952679092549f;   // (1-ALPHA)*(1-BETA)
static constexpr float C2_F    = 0.08822169643436166f;  // ALPHA*(1-BETA)
static constexpr float INV_DEG = 1.0f / 17.0f;

typedef __attribute__((ext_vector_type(8))) short bf16x8;
typedef __attribute__((ext_vector_type(4))) float f32x4;

__device__ __forceinline__ unsigned pack_bf16x2(float a, float b) {
    unsigned ua = __float_as_uint(a), ub = __float_as_uint(b);
    ua += 0x7fffu + ((ua >> 16) & 1u);     // RNE
    ub += 0x7fffu + ((ub >> 16) & 1u);
    return (ua >> 16) | (ub & 0xffff0000u);
}
__device__ __forceinline__ float bflo(unsigned u) { return __uint_as_float(u << 16); }
__device__ __forceinline__ float bfhi(unsigned u) { return __uint_as_float(u & 0xffff0000u); }

// ---------------------------------------------------------------------------
// Kernel 1 (prep) — identical to R7 (best-known): grid = 128 + 1250 blocks.
//   blocks 0..127    : folded-W fragment build (parallel, 1 elem/thread).
//   blocks 128..1377 : transpose+cast 32n x 128c of x -> xTb [N][64] u32.
// W'[c][o] = c<128 ? (BETA*W1[o][c] + (c==o)*C1) * INV_DEG
//                  : BETA*W2[o][c-128] + (c-128==o)*C2
// ---------------------------------------------------------------------------
__global__ __launch_bounds__(256) void prep_kernel(
        const float* __restrict__ x,
        const float* __restrict__ W1,
        const float* __restrict__ W2,
        unsigned* __restrict__ xTb,
        unsigned short* __restrict__ WB) {
    __shared__ unsigned lds[32 * 65];   // [n][c2], stride 65 u32 (8320 B)

    const int b = blockIdx.x;
    const int tid = threadIdx.x;

    if (b < 128) {
        const int i = b * 256 + tid;                   // 0 .. 32767
        const int frag = i >> 9, within = i & 511;
        const int lane = within >> 3, j = within & 7;
        const int otile = frag >> 3, kblk = frag & 7;
        const int o = otile * 16 + (lane & 15);
        const int c = kblk * 32 + ((lane >> 4) << 3) + j;
        float v;
        if (c < 128) {
            v = (BETA_F * W1[o * 128 + c] + (c == o ? C1_F : 0.0f)) * INV_DEG;
        } else {
            const int c2 = c - 128;
            v = BETA_F * W2[o * 128 + c2] + (c2 == o ? C2_F : 0.0f);
        }
        unsigned u = __float_as_uint(v);
        u += 0x7fffu + ((u >> 16) & 1u);
        WB[i] = (unsigned short)(u >> 16);
        return;
    }

    const int nb = (b - 128) * 32;

    const int c2 = tid >> 2;          // 0..63
    const int h  = tid & 3;           // n-offset h*8
    const float* r0 = &x[(size_t)(2 * c2)     * N_NODES + nb + h * 8];
    const float* r1 = &x[(size_t)(2 * c2 + 1) * N_NODES + nb + h * 8];
    const float4 a0 = *(const float4*)(r0);
    const float4 a1 = *(const float4*)(r0 + 4);
    const float4 b0 = *(const float4*)(r1);
    const float4 b1 = *(const float4*)(r1 + 4);

    unsigned* lrow = &lds[h * 8 * 65 + c2];
    lrow[0 * 65] = pack_bf16x2(a0.x, b0.x);
    lrow[1 * 65] = pack_bf16x2(a0.y, b0.y);
    lrow[2 * 65] = pack_bf16x2(a0.z, b0.z);
    lrow[3 * 65] = pack_bf16x2(a0.w, b0.w);
    lrow[4 * 65] = pack_bf16x2(a1.x, b1.x);
    lrow[5 * 65] = pack_bf16x2(a1.y, b1.y);
    lrow[6 * 65] = pack_bf16x2(a1.z, b1.z);
    lrow[7 * 65] = pack_bf16x2(a1.w, b1.w);
    __syncthreads();

    const int n = tid >> 3, q = tid & 7;
    const unsigned* src = &lds[n * 65 + q * 8];
    unsigned* dst = &xTb[(size_t)(nb + n) * 64 + q * 8];
    *(uint4*)&dst[0] = make_uint4(src[0], src[1], src[2], src[3]);
    *(uint4*)&dst[4] = make_uint4(src[4], src[5], src[6], src[7]);
}

// ---------------------------------------------------------------------------
// Kernel 2 (fused): gather-sum (channel-quarter passes, L2-resident) +
// MFMA GEMM (folded W') + relu/bias epilogue.
// Block = 256 threads (4 waves), 32 nodes/block, grid = 1250.
// Gather pass q touches only xTb[:, q*16 .. q*16+16) = 2.56 MB < 4 MB/XCD L2.
// ---------------------------------------------------------------------------
__global__ __launch_bounds__(256) void fused4_kernel(
        const unsigned* __restrict__ xTb,     // [N][64] u32 = bf16x2
        const float*    __restrict__ x0,      // [N][128] f32
        const int*      __restrict__ e0,      // [N][16]
        const bf16x8*   __restrict__ WB,      // 64 frags x 64 lanes x 16B
        const float*    __restrict__ bias,    // [128]
        float*          __restrict__ out) {   // [128][N]
    __shared__ unsigned y[32][132];           // [node][sum(64) | x0(64) | pad 4]
    __shared__ int eis[512];

    const int nb   = blockIdx.x * 32;
    const int tid  = threadIdx.x;
    const int lane = tid & 63;
    const int wid  = tid >> 6;

    eis[tid]       = e0[(size_t)nb * K_NBR + tid];
    eis[256 + tid] = e0[(size_t)nb * K_NBR + 256 + tid];
    __syncthreads();

    // ---- Phase 1a: stage x0 tile (bf16) — issued early, independent ----
    const int node = tid >> 3;        // 0..31
    const int g8   = tid & 7;         // 0..7
    {
        const float* r = &x0[(size_t)(nb + node) * C_DIM + g8 * 16];
        const float4 v0 = *(const float4*)(r);
        const float4 v1 = *(const float4*)(r + 4);
        const float4 v2 = *(const float4*)(r + 8);
        const float4 v3 = *(const float4*)(r + 12);
        uint4 ua, ub;
        ua.x = pack_bf16x2(v0.x, v0.y);  ua.y = pack_bf16x2(v0.z, v0.w);
        ua.z = pack_bf16x2(v1.x, v1.y);  ua.w = pack_bf16x2(v1.z, v1.w);
        ub.x = pack_bf16x2(v2.x, v2.y);  ub.y = pack_bf16x2(v2.z, v2.w);
        ub.z = pack_bf16x2(v3.x, v3.y);  ub.w = pack_bf16x2(v3.z, v3.w);
        *(uint4*)&y[node][64 + g8 * 8]     = ua;
        *(uint4*)&y[node][64 + g8 * 8 + 4] = ub;
    }

    // ---- Phase 1b: neighbor indices -> registers (statically indexed) ----
    int jreg[K_NBR];
#pragma unroll
    for (int k = 0; k < K_NBR; ++k) jreg[k] = eis[node * K_NBR + k];

    // ---- Phase 1c: gather-sum in 4 channel-quarter passes ----
#pragma unroll 1
    for (int q = 0; q < 4; ++q) {
        const int off = q * 16 + 2 * g8;          // u32 offset within row
        const uint2 sv = *(const uint2*)&xTb[(size_t)(nb + node) * 64 + off];
        float s0 = bflo(sv.x), s1 = bfhi(sv.x);
        float s2 = bflo(sv.y), s3 = bfhi(sv.y);
#pragma unroll
        for (int k = 0; k < K_NBR; ++k) {
            const uint2 v = *(const uint2*)&xTb[(size_t)jreg[k] * 64 + off];
            s0 += bflo(v.x); s1 += bfhi(v.x);
            s2 += bflo(v.y); s3 += bfhi(v.y);
        }
        *(uint2*)&y[node][off] =
            make_uint2(pack_bf16x2(s0, s1), pack_bf16x2(s2, s3));
    }
    __syncthreads();

    // ---- Phase 2: MFMA GEMM (K=256) — unchanged from R7 ----
    const int nh = wid & 1;
    const int oh = wid >> 1;
    const int arow = nh * 16 + (lane & 15);
    const int acol = (lane >> 4) * 4;

    bf16x8 afrag[8];
#pragma unroll
    for (int kb = 0; kb < 8; ++kb)
        afrag[kb] = *(const bf16x8*)&y[arow][kb * 16 + acol];

    f32x4 acc[4];
#pragma unroll
    for (int t = 0; t < 4; ++t) {
        f32x4 a = {0.f, 0.f, 0.f, 0.f};
#pragma unroll
        for (int kb = 0; kb < 8; ++kb) {
            bf16x8 bv = WB[((oh * 4 + t) * 8 + kb) * 64 + lane];
            a = __builtin_amdgcn_mfma_f32_16x16x32_bf16(afrag[kb], bv, a, 0, 0, 0);
        }
        acc[t] = a;
    }

    // ---- Phase 3: relu(acc + bias), store [C][N] — unchanged ----
    const int rbase = nh * 16 + (lane >> 4) * 4;
#pragma unroll
    for (int t = 0; t < 4; ++t) {
        const int o = oh * 64 + t * 16 + (lane & 15);
        const float bo = bias[o];
        float4 res;
        res.x = fmaxf(acc[t][0] + bo, 0.0f);
        res.y = fmaxf(acc[t][1] + bo, 0.0f);
        res.z = fmaxf(acc[t][2] + bo, 0.0f);
        res.w = fmaxf(acc[t][3] + bo, 0.0f);
        *(float4*)&out[(size_t)o * N_NODES + nb + rbase] = res;
    }
}

// ---------------------------------------------------------------------------
extern "C" void kernel_launch(void* const* d_in, const int* in_sizes, int n_in,
                              void* d_out, int out_size, void* d_ws, size_t ws_size,
                              hipStream_t stream) {
    const float* x    = (const float*)d_in[0];   // [1,128,40000,1]
    const float* x0   = (const float*)d_in[1];   // [1,40000,128]
    const int*   ei   = (const int*)  d_in[2];   // [2,1,40000,16]; row 0
    const float* W1   = (const float*)d_in[3];   // [128,128]
    const float* W2   = (const float*)d_in[4];   // [128,128]
    const float* bias = (const float*)d_in[5];   // [128]
    float* out = (float*)d_out;                  // [1,128,40000,1]

    // ws: [0, 64KB) WB' bf16 frags ; [64KB, 64KB+10.24MB) xTb
    unsigned short* WB  = (unsigned short*)d_ws;
    unsigned*       xTb = (unsigned*)((char*)d_ws + 65536);

    hipLaunchKernelGGL(prep_kernel, dim3(1378), dim3(256), 0, stream,
                       x, W1, W2, xTb, WB);
    hipLaunchKernelGGL(fused4_kernel, dim3(1250), dim3(256), 0, stream,
                       xTb, x0, ei, (const bf16x8*)WB, bias, out);
}